// Round 2
// baseline (1138.768 us; speedup 1.0000x reference)
//
#include <hip/hip_runtime.h>
#include <stdint.h>

// MultiheadAttention_59150289601069 — MI355X bf16-MFMA implementation.
// Peak d_ws use ~186 MB (pe GEMM runs in 2 K-phases to halve im2col buffer).

typedef __bf16 bf16x8 __attribute__((ext_vector_type(8)));
typedef float f32x4 __attribute__((ext_vector_type(4)));
typedef unsigned short u16;

__device__ __forceinline__ u16 f2b(float f) {
  union { float f; uint32_t u; } v; v.f = f;
  uint32_t u = v.u;
  return (u16)((u + 0x7fffu + ((u >> 16) & 1u)) >> 16);  // RNE
}

__device__ __forceinline__ void g2lds16(const void* g, void* l) {
  __builtin_amdgcn_global_load_lds((__attribute__((address_space(1))) void*)(void*)g,
                                   (__attribute__((address_space(3))) void*)l, 16, 0, 0);
}

// ---------------- mask: 16x16 avg-pool > 0 ----------------
__global__ void k_maskf(const float* __restrict__ mask_map, float* __restrict__ maskf) {
  int p = blockIdx.x * 256 + threadIdx.x;
  if (p >= 704) return;
  int gh = p / 44, gw = p - gh * 44;
  float s = 0.f;
  for (int i = 0; i < 16; ++i)
    for (int j = 0; j < 16; ++j)
      s += mask_map[(gh * 16 + i) * 704 + gw * 16 + j];
  maskf[p] = ((s * (1.f / 256.f)) > 0.f) ? 1.f : 0.f;
}

// ---------------- im2col + f32->bf16 ----------------
// pe: (256,256,704) -> A (768 x 32768) bf16 for k in [kbase, kbase+32768)
__global__ void k_im2col_pe(const float* __restrict__ pe, const int* __restrict__ featp,
                            u16* __restrict__ A, int kbase) {
  int n = blockIdx.x * 256 + threadIdx.x;       // < 768*8192
  int r = n >> 13;
  int kl4 = (n & 8191) << 2;                    // local k (bf16 quad)
  u16 o0 = 0, o1 = 0, o2 = 0, o3 = 0;
  if (r < 704) {
    int k4 = kl4 + kbase;
    int c = k4 >> 8, rem = k4 & 255, i = rem >> 4, j = rem & 15;
    int gh = r / 44, gw = r - gh * 44;
    const float* src = pe + (size_t)featp[0] * (256 * 256 * 704)
                     + ((size_t)(c * 256 + gh * 16 + i)) * 704 + gw * 16 + j;
    f32x4 v = *(const f32x4*)src;
    o0 = f2b(v[0]); o1 = f2b(v[1]); o2 = f2b(v[2]); o3 = f2b(v[3]);
  }
  u16* d = A + (size_t)r * 32768 + kl4;
  d[0] = o0; d[1] = o1; d[2] = o2; d[3] = o3;
}

// x: (6,3,256,704) -> A (4224 x 768) bf16
__global__ void k_im2col_x(const float* __restrict__ x, u16* __restrict__ A) {
  int n = blockIdx.x * 256 + threadIdx.x;       // < 4224*192
  int r = n / 192;
  int k4 = (n - r * 192) << 2;
  int c = k4 >> 8, rem = k4 & 255, i = rem >> 4, j = rem & 15;
  int vv = r / 704, s = r - vv * 704;
  int gh = s / 44, gw = s - gh * 44;
  const float* src = x + ((size_t)(vv * 3 + c) * 256 + gh * 16 + i) * 704 + gw * 16 + j;
  f32x4 v = *(const f32x4*)src;
  u16* d = A + ((size_t)n << 2);
  d[0] = f2b(v[0]); d[1] = f2b(v[1]); d[2] = f2b(v[2]); d[3] = f2b(v[3]);
}

// generic f32 -> bf16 cast (vec4)
__global__ void k_cast(const float* __restrict__ s, u16* __restrict__ d, int n4) {
  int i = blockIdx.x * 256 + threadIdx.x;
  if (i >= n4) return;
  f32x4 v = *((const f32x4*)s + i);
  u16* p = d + ((size_t)i << 2);
  p[0] = f2b(v[0]); p[1] = f2b(v[1]); p[2] = f2b(v[2]); p[3] = f2b(v[3]);
}

// ---------------- bf16 GEMM, C = A(MxKa) * B^T(NxKb slice), m97-style ----------------
// A k-index is local (0..kchunk*gridDim.z); B k-index is k0b + local.
// Partial mode (Cpart != null): writes split-k partials [ks_off+ks][M][N].
// Direct mode: C = (A*B^T + bias) * maskf[row%704], f32 and/or bf16 outs, rows < valid_rows.
__global__ void gemm_bt(const u16* __restrict__ A, const u16* __restrict__ B,
                        int M, int N, int Ka, int Kb, int k0b, int kchunk,
                        float* __restrict__ Cpart, int ks_off,
                        float* __restrict__ Cf, u16* __restrict__ Cb,
                        const float* __restrict__ bias,
                        const float* __restrict__ maskf,
                        int valid_rows) {
  __shared__ __attribute__((aligned(16))) u16 As[128 * 32];
  __shared__ __attribute__((aligned(16))) u16 Bs[128 * 32];
  const int tid = threadIdx.x;
  const int lane = tid & 63, wid = tid >> 6;
  const int tn = blockIdx.x, tm = blockIdx.y, ks = blockIdx.z;
  const int wm = (wid >> 1) * 64, wn = (wid & 1) * 64;
  const int la = lane & 15;
  const int lk = (lane >> 4) * 8;
  f32x4 acc[4][4] = {};

  const int c0 = tid, c1 = tid + 256;
  const u16* ga0 = A + (size_t)(tm * 128 + (c0 >> 2)) * Ka + (c0 & 3) * 8;
  const u16* ga1 = A + (size_t)(tm * 128 + (c1 >> 2)) * Ka + (c1 & 3) * 8;
  const u16* gb0 = B + (size_t)(tn * 128 + (c0 >> 2)) * Kb + k0b + (c0 & 3) * 8;
  const u16* gb1 = B + (size_t)(tn * 128 + (c1 >> 2)) * Kb + k0b + (c1 & 3) * 8;
  u16* lA0 = As + wid * 512;          // wave-uniform LDS base; HW adds lane*16B
  u16* lA1 = As + 2048 + wid * 512;
  u16* lB0 = Bs + wid * 512;
  u16* lB1 = Bs + 2048 + wid * 512;

  const int k0 = ks * kchunk;
  const int nk = kchunk >> 5;
  for (int kk = 0; kk < nk; ++kk) {
    const int kc = k0 + (kk << 5);
    __syncthreads();                   // prior compute done before overwrite
    g2lds16(ga0 + kc, lA0);
    g2lds16(ga1 + kc, lA1);
    g2lds16(gb0 + kc, lB0);
    g2lds16(gb1 + kc, lB1);
    __syncthreads();                   // drains vmcnt -> tiles valid
    bf16x8 af[4], bfr[4];
#pragma unroll
    for (int m = 0; m < 4; ++m)
      af[m] = *(const bf16x8*)&As[(wm + m * 16 + la) * 32 + lk];
#pragma unroll
    for (int n = 0; n < 4; ++n)
      bfr[n] = *(const bf16x8*)&Bs[(wn + n * 16 + la) * 32 + lk];
#pragma unroll
    for (int m = 0; m < 4; ++m)
#pragma unroll
      for (int n = 0; n < 4; ++n)
        acc[m][n] = __builtin_amdgcn_mfma_f32_16x16x32_bf16(af[m], bfr[n], acc[m][n], 0, 0, 0);
  }

  const int r0 = tm * 128 + wm + (lane >> 4) * 4;   // C/D: col=lane&15, row=(lane>>4)*4+reg
  const int cc = tn * 128 + wn + la;
  if (Cpart != nullptr) {
#pragma unroll
    for (int m = 0; m < 4; ++m)
#pragma unroll
      for (int n = 0; n < 4; ++n) {
        float* p = Cpart + ((size_t)(ks + ks_off) * M + (r0 + m * 16)) * N + cc + n * 16;
#pragma unroll
        for (int r = 0; r < 4; ++r) p[(size_t)r * N] = acc[m][n][r];
      }
  } else {
#pragma unroll
    for (int m = 0; m < 4; ++m)
#pragma unroll
      for (int r = 0; r < 4; ++r) {
        int row = r0 + m * 16 + r;
        if (row < valid_rows) {
          float mk = maskf ? maskf[row % 704] : 1.f;
#pragma unroll
          for (int n = 0; n < 4; ++n) {
            int col = cc + n * 16;
            float v = acc[m][n][r];
            if (bias) v += bias[col];
            v *= mk;
            if (Cf) Cf[(size_t)row * N + col] = v;
            if (Cb) Cb[(size_t)row * N + col] = f2b(v);
          }
        }
      }
  }
}

// reduce 16 split-k partials of pe conv, + bias, * mask -> pe_tok f32 (704x512)
__global__ void k_reduce_pe(const float* __restrict__ Cpart, const float* __restrict__ bias,
                            const float* __restrict__ maskf, float* __restrict__ pe_tok) {
  int n = blockIdx.x * 256 + threadIdx.x;       // < 704*128
  int r = n >> 7;
  int c4 = (n & 127) << 2;
  f32x4 acc = {};
  for (int ks = 0; ks < 16; ++ks)
    acc += *(const f32x4*)(Cpart + ((size_t)ks * 768 + r) * 512 + c4);
  f32x4 b = *(const f32x4*)(bias + c4);
  float mk = maskf[r];
  f32x4 o = (acc + b) * mk;
  *(f32x4*)(pe_tok + (size_t)r * 512 + c4) = o;
}

// ---------------- attention prep ----------------
// qn[h][s][d] = l2norm(q[feat,h,s,:] + fpe[h,s,:])
__global__ void k_prep_q(const float* __restrict__ qkv, const float* __restrict__ pe_tok,
                         const int* __restrict__ featp, float* __restrict__ qn) {
  int rid = blockIdx.x * 4 + (threadIdx.x >> 6);  // < 5632 = 8*704
  int lane = threadIdx.x & 63;
  int h = rid / 704, s = rid - h * 704;
  int f = featp[0];
  float v = qkv[((size_t)(f * 704 + s)) * 1536 + h * 192 + lane]
          + pe_tok[(size_t)s * 512 + h * 64 + lane];
  float ss = v * v;
#pragma unroll
  for (int m = 32; m; m >>= 1) ss += __shfl_xor(ss, m);
  float nrm = fmaxf(sqrtf(ss), 1e-12f);
  qn[(size_t)rid * 64 + lane] = v / nrm;
}

// kn[h][t][d] = l2norm(k of other views), vc = v of other views (raw)
__global__ void k_prep_kv(const float* __restrict__ qkv, const int* __restrict__ featp,
                          float* __restrict__ kn, float* __restrict__ vc) {
  int rid = blockIdx.x * 4 + (threadIdx.x >> 6);  // < 28160 = 8*3520
  int lane = threadIdx.x & 63;
  int h = rid / 3520, t = rid - h * 3520;
  int o = t / 704, s = t - o * 704;
  int f = featp[0];
  int view = o + (o >= f ? 1 : 0);
  size_t base = ((size_t)(view * 704 + s)) * 1536 + h * 192;
  float kv = qkv[base + 64 + lane];
  float vv = qkv[base + 128 + lane];
  float ss = kv * kv;
#pragma unroll
  for (int m = 32; m; m >>= 1) ss += __shfl_xor(ss, m);
  float nrm = fmaxf(sqrtf(ss), 1e-12f);
  kn[(size_t)rid * 64 + lane] = kv / nrm;
  vc[(size_t)rid * 64 + lane] = vv;
}

// landmark means: qL (8,16,64) over bins of 44; kL (8,16,64) over bins of 220
__global__ void k_landmarks(const float* __restrict__ qn, const float* __restrict__ kn,
                            float* __restrict__ qL, float* __restrict__ kL) {
  int t = blockIdx.x * 256 + threadIdx.x;         // < 16384
  if (t < 8192) {
    int h = t >> 10, rem = t & 1023, l = rem >> 6, d = rem & 63;
    float s = 0.f;
    for (int u = 0; u < 44; ++u) s += qn[((size_t)h * 704 + l * 44 + u) * 64 + d];
    qL[t] = s * (1.f / 44.f);
  } else {
    int tt = t - 8192;
    int h = tt >> 10, rem = tt & 1023, l = rem >> 6, d = rem & 63;
    float s = 0.f;
    for (int u = 0; u < 220; ++u) s += kn[((size_t)h * 3520 + l * 220 + u) * 64 + d];
    kL[tt] = s * (1.f / 220.f);
  }
}

// a1[h][s][l] = softmax_l( qn . kL / 8 )
__global__ void k_a1(const float* __restrict__ qn, const float* __restrict__ kL,
                     float* __restrict__ a1) {
  int rid = blockIdx.x * 4 + (threadIdx.x >> 6);  // < 5632
  int lane = threadIdx.x & 63;
  int h = rid / 704;
  float q = qn[(size_t)rid * 64 + lane];
  float lg[16];
#pragma unroll
  for (int l = 0; l < 16; ++l) {
    float p = q * kL[(h * 16 + l) * 64 + lane];
#pragma unroll
    for (int m = 32; m; m >>= 1) p += __shfl_xor(p, m);
    lg[l] = p * 0.125f;
  }
  float mx = lg[0];
#pragma unroll
  for (int l = 1; l < 16; ++l) mx = fmaxf(mx, lg[l]);
  float sum = 0.f;
#pragma unroll
  for (int l = 0; l < 16; ++l) { lg[l] = expf(lg[l] - mx); sum += lg[l]; }
  float inv = 1.f / sum;
  float outv = 0.f;
#pragma unroll
  for (int l = 0; l < 16; ++l) if (lane == l) outv = lg[l] * inv;   // static indexing
  if (lane < 16) a1[(size_t)rid * 16 + lane] = outv;
}

// tmp[h][l][d] = softmax_t( qL . kn / 8 ) @ vc  — fused per (h,l) block
__global__ void k_a2tmp(const float* __restrict__ qL, const float* __restrict__ kn,
                        const float* __restrict__ vc, float* __restrict__ tmp) {
  int hl = blockIdx.x;                  // < 128
  int h = hl >> 4;
  int tid = threadIdx.x, lane = tid & 63, w = tid >> 6;
  __shared__ float p[3520];
  __shared__ float red[8];
  __shared__ float part[4][64];
  float qv = qL[(size_t)hl * 64 + lane];
  for (int t = w; t < 3520; t += 4) {
    float prod = qv * kn[((size_t)h * 3520 + t) * 64 + lane];
#pragma unroll
    for (int m = 32; m; m >>= 1) prod += __shfl_xor(prod, m);
    if (lane == 0) p[t] = prod * 0.125f;
  }
  __syncthreads();
  float mx = -1e30f;
  for (int t = tid; t < 3520; t += 256) mx = fmaxf(mx, p[t]);
#pragma unroll
  for (int m = 32; m; m >>= 1) mx = fmaxf(mx, __shfl_xor(mx, m));
  if (lane == 0) red[w] = mx;
  __syncthreads();
  mx = fmaxf(fmaxf(red[0], red[1]), fmaxf(red[2], red[3]));
  float sm = 0.f;
  for (int t = tid; t < 3520; t += 256) { float e = expf(p[t] - mx); p[t] = e; sm += e; }
#pragma unroll
  for (int m = 32; m; m >>= 1) sm += __shfl_xor(sm, m);
  if (lane == 0) red[4 + w] = sm;
  __syncthreads();
  sm = red[4] + red[5] + red[6] + red[7];
  float accv = 0.f;
  for (int t = w * 880; t < (w + 1) * 880; ++t)
    accv += p[t] * vc[((size_t)h * 3520 + t) * 64 + lane];
  part[w][lane] = accv;
  __syncthreads();
  if (w == 0) {
    float v = part[0][lane] + part[1][lane] + part[2][lane] + part[3][lane];
    tmp[(size_t)hl * 64 + lane] = v / sm;
  }
}

// vals_b[s][h*64+d] = bf16( sum_l a1[h,s,l]*tmp[h,l,d] ); rows 704..767 zero
__global__ void k_vals(const float* __restrict__ a1, const float* __restrict__ tmp,
                       u16* __restrict__ vals_b) {
  int idx = blockIdx.x * 256 + threadIdx.x;       // < 768*512
  int s = idx >> 9;
  int col = idx & 511;
  int h = col >> 6, d = col & 63;
  float v = 0.f;
  if (s < 704) {
    const float* ar = a1 + ((size_t)h * 704 + s) * 16;
    const float* tr = tmp + (size_t)h * 16 * 64 + d;
#pragma unroll
    for (int l = 0; l < 16; ++l) v += ar[l] * tr[l * 64];
  }
  vals_b[idx] = f2b(v);
}

extern "C" void kernel_launch(void* const* d_in, const int* in_sizes, int n_in,
                              void* d_out, int out_size, void* d_ws, size_t ws_size,
                              hipStream_t stream) {
  const float* x    = (const float*)d_in[0];
  const float* pe   = (const float*)d_in[1];
  const float* mask = (const float*)d_in[2];
  const float* ciw  = (const float*)d_in[3];
  const float* cib  = (const float*)d_in[4];
  const float* cpw  = (const float*)d_in[5];
  const float* cpb  = (const float*)d_in[6];
  const float* qkvw = (const float*)d_in[7];
  const float* qkvb = (const float*)d_in[8];
  const float* ow   = (const float*)d_in[9];
  const float* ob   = (const float*)d_in[10];
  const int* featp  = (const int*)d_in[11];
  float* out = (float*)d_out;
  (void)in_sizes; (void)n_in; (void)out_size; (void)ws_size;

  char* w = (char*)d_ws;
  size_t off = 0;
  auto take = [&](size_t b) { char* p = w + off; off = (off + b + 255) & ~(size_t)255; return p; };
  float* maskf  = (float*)take(704 * 4);
  float* pe_tok = (float*)take((size_t)768 * 512 * 4);
  float* qkv    = (float*)take((size_t)4224 * 1536 * 4);
  float* qn     = (float*)take((size_t)5632 * 64 * 4);
  float* kn     = (float*)take((size_t)28160 * 64 * 4);
  float* vc     = (float*)take((size_t)28160 * 64 * 4);
  float* qL     = (float*)take(8192 * 4);
  float* kL     = (float*)take(8192 * 4);
  float* a1     = (float*)take((size_t)5632 * 16 * 4);
  float* tmp    = (float*)take(8192 * 4);
  // big arena: pe phase {A_pe(50.3MB), B_pe(67.1MB), Cpart(25.2MB)}; later phases overlay
  char* arena = take((size_t)50331648 + 67108864 + 25165824);
  u16* A_pe    = (u16*)arena;                                  // 768 x 32768 bf16
  u16* B_pe    = (u16*)(arena + 50331648);                     // 512 x 65536 bf16
  float* Cpart = (float*)(arena + 50331648 + 67108864);        // 16 x 768 x 512 f32
  u16* A_x    = (u16*)arena;                                   // 4224 x 768
  u16* B_xw   = (u16*)(arena + 6488064);                       // 512 x 768
  u16* tok_b  = (u16*)(arena + 6488064 + 786432);              // 4224 x 512
  u16* qkvW_b = (u16*)(arena + 6488064 + 786432 + 4325376);    // 1536 x 512
  u16* oW_b   = (u16*)(arena + 6488064 + 786432 + 4325376 + 1572864);            // 512 x 512
  u16* vals_b = (u16*)(arena + 6488064 + 786432 + 4325376 + 1572864 + 524288);   // 768 x 512

  k_maskf<<<3, 256, 0, stream>>>(mask, maskf);

  // --- pe patch-embed: (704x65536) @ (512x65536)^T, 2 phases x split-K=8 ---
  k_cast<<<32768, 256, 0, stream>>>(cpw, B_pe, 8388608);
  for (int p = 0; p < 2; ++p) {
    k_im2col_pe<<<24576, 256, 0, stream>>>(pe, featp, A_pe, p * 32768);
    gemm_bt<<<dim3(4, 6, 8), 256, 0, stream>>>(A_pe, B_pe, 768, 512, 32768, 65536,
                                               p * 32768, 4096, Cpart, p * 8,
                                               nullptr, nullptr, nullptr, nullptr, 0);
  }
  k_reduce_pe<<<352, 256, 0, stream>>>(Cpart, cpb, maskf, pe_tok);

  // --- x patch-embed + mask -> tokens bf16 ---
  k_im2col_x<<<3168, 256, 0, stream>>>(x, A_x);
  k_cast<<<384, 256, 0, stream>>>(ciw, B_xw, 98304);
  gemm_bt<<<dim3(4, 33, 1), 256, 0, stream>>>(A_x, B_xw, 4224, 512, 768, 768, 0, 768,
                                              nullptr, 0, nullptr, tok_b, cib, maskf, 4224);

  // --- qkv projection ---
  k_cast<<<768, 256, 0, stream>>>(qkvw, qkvW_b, 196608);
  gemm_bt<<<dim3(12, 33, 1), 256, 0, stream>>>(tok_b, qkvW_b, 4224, 1536, 512, 512, 0, 512,
                                               nullptr, 0, qkv, nullptr, qkvb, nullptr, 4224);

  // --- landmark attention (fp32) ---
  k_prep_q<<<1408, 256, 0, stream>>>(qkv, pe_tok, featp, qn);
  k_prep_kv<<<7040, 256, 0, stream>>>(qkv, featp, kn, vc);
  k_landmarks<<<64, 256, 0, stream>>>(qn, kn, qL, kL);
  k_a1<<<1408, 256, 0, stream>>>(qn, kL, a1);
  k_a2tmp<<<128, 256, 0, stream>>>(qL, kn, vc, tmp);
  k_vals<<<1536, 256, 0, stream>>>(a1, tmp, vals_b);

  // --- output projection -> d_out ---
  k_cast<<<256, 256, 0, stream>>>(ow, oW_b, 65536);
  gemm_bt<<<dim3(4, 6, 1), 256, 0, stream>>>(vals_b, oW_b, 768, 512, 512, 512, 0, 512,
                                             nullptr, 0, out, nullptr, ob, nullptr, 704);
}

// Round 3
// 724.912 us; speedup vs baseline: 1.5709x; 1.5709x over previous
//
#include <hip/hip_runtime.h>
#include <stdint.h>

// MultiheadAttention_59150289601069 — MI355X bf16-MFMA implementation.
// Peak d_ws use ~190 MB.

typedef __bf16 bf16x8 __attribute__((ext_vector_type(8)));
typedef float f32x4 __attribute__((ext_vector_type(4)));
typedef unsigned short u16;

__device__ __forceinline__ u16 f2b(float f) {
  union { float f; uint32_t u; } v; v.f = f;
  uint32_t u = v.u;
  return (u16)((u + 0x7fffu + ((u >> 16) & 1u)) >> 16);  // RNE
}

__device__ __forceinline__ void g2lds16(const void* g, void* l) {
  __builtin_amdgcn_global_load_lds((__attribute__((address_space(1))) void*)(void*)g,
                                   (__attribute__((address_space(3))) void*)l, 16, 0, 0);
}

// ---------------- mask: 16x16 avg-pool > 0 ----------------
__global__ void k_maskf(const float* __restrict__ mask_map, float* __restrict__ maskf) {
  int p = blockIdx.x * 256 + threadIdx.x;
  if (p >= 704) return;
  int gh = p / 44, gw = p - gh * 44;
  float s = 0.f;
  for (int i = 0; i < 16; ++i)
    for (int j = 0; j < 16; ++j)
      s += mask_map[(gh * 16 + i) * 704 + gw * 16 + j];
  maskf[p] = ((s * (1.f / 256.f)) > 0.f) ? 1.f : 0.f;
}

// ---------------- im2col + f32->bf16 ----------------
// pe: (256,256,704) -> A (768 x 32768) bf16 for k in [kbase, kbase+32768)
__global__ void k_im2col_pe(const float* __restrict__ pe, const int* __restrict__ featp,
                            u16* __restrict__ A, int kbase) {
  int n = blockIdx.x * 256 + threadIdx.x;       // < 768*8192
  int r = n >> 13;
  int kl4 = (n & 8191) << 2;                    // local k (bf16 quad)
  u16 o0 = 0, o1 = 0, o2 = 0, o3 = 0;
  if (r < 704) {
    int k4 = kl4 + kbase;
    int c = k4 >> 8, rem = k4 & 255, i = rem >> 4, j = rem & 15;
    int gh = r / 44, gw = r - gh * 44;
    const float* src = pe + (size_t)featp[0] * (256 * 256 * 704)
                     + ((size_t)(c * 256 + gh * 16 + i)) * 704 + gw * 16 + j;
    f32x4 v = *(const f32x4*)src;
    o0 = f2b(v[0]); o1 = f2b(v[1]); o2 = f2b(v[2]); o3 = f2b(v[3]);
  }
  u16* d = A + (size_t)r * 32768 + kl4;
  d[0] = o0; d[1] = o1; d[2] = o2; d[3] = o3;
}

// x: (6,3,256,704) -> A (4224 x 768) bf16
__global__ void k_im2col_x(const float* __restrict__ x, u16* __restrict__ A) {
  int n = blockIdx.x * 256 + threadIdx.x;       // < 4224*192
  int r = n / 192;
  int k4 = (n - r * 192) << 2;
  int c = k4 >> 8, rem = k4 & 255, i = rem >> 4, j = rem & 15;
  int vv = r / 704, s = r - vv * 704;
  int gh = s / 44, gw = s - gh * 44;
  const float* src = x + ((size_t)(vv * 3 + c) * 256 + gh * 16 + i) * 704 + gw * 16 + j;
  f32x4 v = *(const f32x4*)src;
  u16* d = A + ((size_t)n << 2);
  d[0] = f2b(v[0]); d[1] = f2b(v[1]); d[2] = f2b(v[2]); d[3] = f2b(v[3]);
}

// generic f32 -> bf16 cast (vec4)
__global__ void k_cast(const float* __restrict__ s, u16* __restrict__ d, int n4) {
  int i = blockIdx.x * 256 + threadIdx.x;
  if (i >= n4) return;
  f32x4 v = *((const f32x4*)s + i);
  u16* p = d + ((size_t)i << 2);
  p[0] = f2b(v[0]); p[1] = f2b(v[1]); p[2] = f2b(v[2]); p[3] = f2b(v[3]);
}

// ---------------- bf16 GEMM, C = A(MxKa) * B^T(NxKb slice), m97-style ----------------
// A k-index is local; B k-index is k0b + local.
// Partial mode (Cpart != null): writes/accumulates split-k partials [ks_off+ks][M][N].
// Direct mode: C = (A*B^T + bias) * maskf[row%704], f32 and/or bf16 outs, rows < valid_rows.
__global__ void gemm_bt(const u16* __restrict__ A, const u16* __restrict__ B,
                        int M, int N, int Ka, int Kb, int k0b, int kchunk,
                        float* __restrict__ Cpart, int ks_off, int accum,
                        float* __restrict__ Cf, u16* __restrict__ Cb,
                        const float* __restrict__ bias,
                        const float* __restrict__ maskf,
                        int valid_rows) {
  __shared__ __attribute__((aligned(16))) u16 As[128 * 32];
  __shared__ __attribute__((aligned(16))) u16 Bs[128 * 32];
  const int tid = threadIdx.x;
  const int lane = tid & 63, wid = tid >> 6;
  const int tn = blockIdx.x, tm = blockIdx.y, ks = blockIdx.z;
  const int wm = (wid >> 1) * 64, wn = (wid & 1) * 64;
  const int la = lane & 15;
  const int lk = (lane >> 4) * 8;
  f32x4 acc[4][4] = {};

  const int c0 = tid, c1 = tid + 256;
  const u16* ga0 = A + (size_t)(tm * 128 + (c0 >> 2)) * Ka + (c0 & 3) * 8;
  const u16* ga1 = A + (size_t)(tm * 128 + (c1 >> 2)) * Ka + (c1 & 3) * 8;
  const u16* gb0 = B + (size_t)(tn * 128 + (c0 >> 2)) * Kb + k0b + (c0 & 3) * 8;
  const u16* gb1 = B + (size_t)(tn * 128 + (c1 >> 2)) * Kb + k0b + (c1 & 3) * 8;
  u16* lA0 = As + wid * 512;          // wave-uniform LDS base; HW adds lane*16B
  u16* lA1 = As + 2048 + wid * 512;
  u16* lB0 = Bs + wid * 512;
  u16* lB1 = Bs + 2048 + wid * 512;

  const int k0 = ks * kchunk;
  const int nk = kchunk >> 5;
  for (int kk = 0; kk < nk; ++kk) {
    const int kc = k0 + (kk << 5);
    __syncthreads();                   // prior compute done before overwrite
    g2lds16(ga0 + kc, lA0);
    g2lds16(ga1 + kc, lA1);
    g2lds16(gb0 + kc, lB0);
    g2lds16(gb1 + kc, lB1);
    __syncthreads();                   // drains vmcnt -> tiles valid
    bf16x8 af[4], bfr[4];
#pragma unroll
    for (int m = 0; m < 4; ++m)
      af[m] = *(const bf16x8*)&As[(wm + m * 16 + la) * 32 + lk];
#pragma unroll
    for (int n = 0; n < 4; ++n)
      bfr[n] = *(const bf16x8*)&Bs[(wn + n * 16 + la) * 32 + lk];
#pragma unroll
    for (int m = 0; m < 4; ++m)
#pragma unroll
      for (int n = 0; n < 4; ++n)
        acc[m][n] = __builtin_amdgcn_mfma_f32_16x16x32_bf16(af[m], bfr[n], acc[m][n], 0, 0, 0);
  }

  const int r0 = tm * 128 + wm + (lane >> 4) * 4;   // C/D: col=lane&15, row=(lane>>4)*4+reg
  const int cc = tn * 128 + wn + la;
  if (Cpart != nullptr) {
#pragma unroll
    for (int m = 0; m < 4; ++m)
#pragma unroll
      for (int n = 0; n < 4; ++n) {
        float* p = Cpart + ((size_t)(ks + ks_off) * M + (r0 + m * 16)) * N + cc + n * 16;
        if (accum) {
#pragma unroll
          for (int r = 0; r < 4; ++r) p[(size_t)r * N] += acc[m][n][r];
        } else {
#pragma unroll
          for (int r = 0; r < 4; ++r) p[(size_t)r * N] = acc[m][n][r];
        }
      }
  } else {
#pragma unroll
    for (int m = 0; m < 4; ++m)
#pragma unroll
      for (int r = 0; r < 4; ++r) {
        int row = r0 + m * 16 + r;
        if (row < valid_rows) {
          float mk = maskf ? maskf[row % 704] : 1.f;
#pragma unroll
          for (int n = 0; n < 4; ++n) {
            int col = cc + n * 16;
            float v = acc[m][n][r];
            if (bias) v += bias[col];
            v *= mk;
            if (Cf) Cf[(size_t)row * N + col] = v;
            if (Cb) Cb[(size_t)row * N + col] = f2b(v);
          }
        }
      }
  }
}

// reduce 16 split-k partials of pe conv, + bias, * mask -> pe_tok f32 (704x512)
__global__ void k_reduce_pe(const float* __restrict__ Cpart, const float* __restrict__ bias,
                            const float* __restrict__ maskf, float* __restrict__ pe_tok) {
  int n = blockIdx.x * 256 + threadIdx.x;       // < 704*128
  int r = n >> 7;
  int c4 = (n & 127) << 2;
  f32x4 acc = {};
  for (int ks = 0; ks < 16; ++ks)
    acc += *(const f32x4*)(Cpart + ((size_t)ks * 768 + r) * 512 + c4);
  f32x4 b = *(const f32x4*)(bias + c4);
  float mk = maskf[r];
  f32x4 o = (acc + b) * mk;
  *(f32x4*)(pe_tok + (size_t)r * 512 + c4) = o;
}

// ---------------- attention prep ----------------
// qn[h][s][d] = l2norm(q[feat,h,s,:] + fpe[h,s,:])
__global__ void k_prep_q(const float* __restrict__ qkv, const float* __restrict__ pe_tok,
                         const int* __restrict__ featp, float* __restrict__ qn) {
  int rid = blockIdx.x * 4 + (threadIdx.x >> 6);  // < 5632 = 8*704
  int lane = threadIdx.x & 63;
  int h = rid / 704, s = rid - h * 704;
  int f = featp[0];
  float v = qkv[((size_t)(f * 704 + s)) * 1536 + h * 192 + lane]
          + pe_tok[(size_t)s * 512 + h * 64 + lane];
  float ss = v * v;
#pragma unroll
  for (int m = 32; m; m >>= 1) ss += __shfl_xor(ss, m);
  float nrm = fmaxf(sqrtf(ss), 1e-12f);
  qn[(size_t)rid * 64 + lane] = v / nrm;
}

// knT[h][d][t] = l2norm(k of other views) transposed; vc[h][t][d] = v (raw)
__global__ void k_prep_kv(const float* __restrict__ qkv, const int* __restrict__ featp,
                          float* __restrict__ knT, float* __restrict__ vc) {
  int rid = blockIdx.x * 4 + (threadIdx.x >> 6);  // < 28160 = 8*3520
  int lane = threadIdx.x & 63;
  int h = rid / 3520, t = rid - h * 3520;
  int o = t / 704, s = t - o * 704;
  int f = featp[0];
  int view = o + (o >= f ? 1 : 0);
  size_t base = ((size_t)(view * 704 + s)) * 1536 + h * 192;
  float kv = qkv[base + 64 + lane];
  float vv = qkv[base + 128 + lane];
  float ss = kv * kv;
#pragma unroll
  for (int m = 32; m; m >>= 1) ss += __shfl_xor(ss, m);
  float nrm = fmaxf(sqrtf(ss), 1e-12f);
  knT[((size_t)h * 64 + lane) * 3520 + t] = kv / nrm;
  vc[(size_t)rid * 64 + lane] = vv;
}

// landmark means: qL[h][l][d] over bins of 44 (from qn); kL[h][l][d] over bins of 220 (from knT)
__global__ void k_landmarks(const float* __restrict__ qn, const float* __restrict__ knT,
                            float* __restrict__ qL, float* __restrict__ kL) {
  int t = blockIdx.x * 256 + threadIdx.x;         // < 16384
  if (t < 8192) {
    int h = t >> 10, rem = t & 1023, l = rem >> 6, d = rem & 63;
    float s = 0.f;
    for (int u = 0; u < 44; ++u) s += qn[((size_t)h * 704 + l * 44 + u) * 64 + d];
    qL[t] = s * (1.f / 44.f);
  } else {
    int tt = t - 8192;
    int h = tt >> 10, rem = tt & 1023, l = rem >> 6, d = rem & 63;
    const float* kp = knT + ((size_t)h * 64 + d) * 3520 + l * 220;
    float s = 0.f;
    for (int u = 0; u < 220; ++u) s += kp[u];
    kL[tt] = s * (1.f / 220.f);
  }
}

// a1[h][s][l] = softmax_l( qn . kL / 8 )
__global__ void k_a1(const float* __restrict__ qn, const float* __restrict__ kL,
                     float* __restrict__ a1) {
  int rid = blockIdx.x * 4 + (threadIdx.x >> 6);  // < 5632
  int lane = threadIdx.x & 63;
  int h = rid / 704;
  float q = qn[(size_t)rid * 64 + lane];
  float lg[16];
#pragma unroll
  for (int l = 0; l < 16; ++l) {
    float p = q * kL[(h * 16 + l) * 64 + lane];
#pragma unroll
    for (int m = 32; m; m >>= 1) p += __shfl_xor(p, m);
    lg[l] = p * 0.125f;
  }
  float mx = lg[0];
#pragma unroll
  for (int l = 1; l < 16; ++l) mx = fmaxf(mx, lg[l]);
  float sum = 0.f;
#pragma unroll
  for (int l = 0; l < 16; ++l) { lg[l] = expf(lg[l] - mx); sum += lg[l]; }
  float inv = 1.f / sum;
  float outv = 0.f;
#pragma unroll
  for (int l = 0; l < 16; ++l) if (lane == l) outv = lg[l] * inv;   // static indexing
  if (lane < 16) a1[(size_t)rid * 16 + lane] = outv;
}

// E[h][l][t] = exp( (qL[h][l] . knT[h][:][t]) / 8 )
// logits bounded by |qL||kn|/8 <= 1/8, so no max subtraction needed (exactly
// cancels in softmax normalization anyway).
__global__ void k_a2_logits(const float* __restrict__ qL, const float* __restrict__ knT,
                            float* __restrict__ E) {
  __shared__ float qs[1024];
  int h = blockIdx.y;
  int t = blockIdx.x * 256 + threadIdx.x;
  for (int i = threadIdx.x; i < 1024; i += 256) qs[i] = qL[h * 1024 + i];
  __syncthreads();
  if (t >= 3520) return;
  const float* kp = knT + (size_t)h * 64 * 3520 + t;
  float p[16] = {};
  for (int d = 0; d < 64; ++d) {
    float kv = kp[(size_t)d * 3520];
#pragma unroll
    for (int l = 0; l < 16; ++l) p[l] += qs[l * 64 + d] * kv;
  }
  float* ep = E + (size_t)(h * 16) * 3520 + t;
#pragma unroll
  for (int l = 0; l < 16; ++l) ep[(size_t)l * 3520] = __expf(p[l] * 0.125f);
}

// tmp[h][l][d] = (sum_t E[h][l][t] * vc[h][t][d]) / (sum_t E[h][l][t])
__global__ void k_a2_pv(const float* __restrict__ E, const float* __restrict__ vc,
                        float* __restrict__ tmp) {
  int hl = blockIdx.x;              // < 128
  int h = hl >> 4;
  int tid = threadIdx.x, lane = tid & 63, w = tid >> 6;
  __shared__ float part[4][64];
  __shared__ float psum[4];
  const float* ep = E + (size_t)hl * 3520;
  const float* vp = vc + (size_t)h * 3520 * 64 + lane;
  float acc = 0.f, es = 0.f;
#pragma unroll 8
  for (int t = w; t < 3520; t += 4) {
    float e = ep[t];
    acc += e * vp[(size_t)t * 64];
    es += e;
  }
  part[w][lane] = acc;
  if (lane == 0) psum[w] = es;
  __syncthreads();
  if (w == 0) {
    float v = part[0][lane] + part[1][lane] + part[2][lane] + part[3][lane];
    float s = psum[0] + psum[1] + psum[2] + psum[3];
    tmp[(size_t)hl * 64 + lane] = v / s;
  }
}

// vals_b[s][h*64+d] = bf16( sum_l a1[h,s,l]*tmp[h,l,d] ); rows 704..767 zero
__global__ void k_vals(const float* __restrict__ a1, const float* __restrict__ tmp,
                       u16* __restrict__ vals_b) {
  int idx = blockIdx.x * 256 + threadIdx.x;       // < 768*512
  int s = idx >> 9;
  int col = idx & 511;
  int h = col >> 6, d = col & 63;
  float v = 0.f;
  if (s < 704) {
    const float* ar = a1 + ((size_t)h * 704 + s) * 16;
    const float* tr = tmp + (size_t)h * 16 * 64 + d;
#pragma unroll
    for (int l = 0; l < 16; ++l) v += ar[l] * tr[l * 64];
  }
  vals_b[idx] = f2b(v);
}

extern "C" void kernel_launch(void* const* d_in, const int* in_sizes, int n_in,
                              void* d_out, int out_size, void* d_ws, size_t ws_size,
                              hipStream_t stream) {
  const float* x    = (const float*)d_in[0];
  const float* pe   = (const float*)d_in[1];
  const float* mask = (const float*)d_in[2];
  const float* ciw  = (const float*)d_in[3];
  const float* cib  = (const float*)d_in[4];
  const float* cpw  = (const float*)d_in[5];
  const float* cpb  = (const float*)d_in[6];
  const float* qkvw = (const float*)d_in[7];
  const float* qkvb = (const float*)d_in[8];
  const float* ow   = (const float*)d_in[9];
  const float* ob   = (const float*)d_in[10];
  const int* featp  = (const int*)d_in[11];
  float* out = (float*)d_out;
  (void)in_sizes; (void)n_in; (void)out_size; (void)ws_size;

  char* w = (char*)d_ws;
  size_t off = 0;
  auto take = [&](size_t b) { char* p = w + off; off = (off + b + 255) & ~(size_t)255; return p; };
  float* maskf  = (float*)take(704 * 4);
  float* pe_tok = (float*)take((size_t)768 * 512 * 4);
  float* qkv    = (float*)take((size_t)4224 * 1536 * 4);
  float* qn     = (float*)take((size_t)5632 * 64 * 4);
  float* knT    = (float*)take((size_t)28160 * 64 * 4);
  float* vc     = (float*)take((size_t)28160 * 64 * 4);
  float* qL     = (float*)take(8192 * 4);
  float* kL     = (float*)take(8192 * 4);
  float* a1     = (float*)take((size_t)5632 * 16 * 4);
  float* tmp    = (float*)take(8192 * 4);
  float* E      = (float*)take((size_t)128 * 3520 * 4);
  // big arena: pe phase {A_pe(50.3MB), B_pe(67.1MB), Cpart(25.2MB)}; later phases overlay
  char* arena = take((size_t)50331648 + 67108864 + 25165824);
  u16* A_pe    = (u16*)arena;                                  // 768 x 32768 bf16
  u16* B_pe    = (u16*)(arena + 50331648);                     // 512 x 65536 bf16
  float* Cpart = (float*)(arena + 50331648 + 67108864);        // 16 x 768 x 512 f32
  u16* A_x    = (u16*)arena;                                   // 4224 x 768
  u16* B_xw   = (u16*)(arena + 6488064);                       // 512 x 768
  u16* tok_b  = (u16*)(arena + 6488064 + 786432);              // 4224 x 512
  u16* qkvW_b = (u16*)(arena + 6488064 + 786432 + 4325376);    // 1536 x 512
  u16* oW_b   = (u16*)(arena + 6488064 + 786432 + 4325376 + 1572864);            // 512 x 512
  u16* vals_b = (u16*)(arena + 6488064 + 786432 + 4325376 + 1572864 + 524288);   // 768 x 512

  k_maskf<<<3, 256, 0, stream>>>(mask, maskf);

  // --- pe patch-embed: (704x65536) @ (512x65536)^T, 2 phases x split-K=16 (accum) ---
  k_cast<<<32768, 256, 0, stream>>>(cpw, B_pe, 8388608);
  for (int p = 0; p < 2; ++p) {
    k_im2col_pe<<<24576, 256, 0, stream>>>(pe, featp, A_pe, p * 32768);
    gemm_bt<<<dim3(4, 6, 16), 256, 0, stream>>>(A_pe, B_pe, 768, 512, 32768, 65536,
                                                p * 32768, 2048, Cpart, 0, p,
                                                nullptr, nullptr, nullptr, nullptr, 0);
  }
  k_reduce_pe<<<352, 256, 0, stream>>>(Cpart, cpb, maskf, pe_tok);

  // --- x patch-embed + mask -> tokens bf16 ---
  k_im2col_x<<<3168, 256, 0, stream>>>(x, A_x);
  k_cast<<<384, 256, 0, stream>>>(ciw, B_xw, 98304);
  gemm_bt<<<dim3(4, 33, 1), 256, 0, stream>>>(A_x, B_xw, 4224, 512, 768, 768, 0, 768,
                                              nullptr, 0, 0, nullptr, tok_b, cib, maskf, 4224);

  // --- qkv projection ---
  k_cast<<<768, 256, 0, stream>>>(qkvw, qkvW_b, 196608);
  gemm_bt<<<dim3(12, 33, 1), 256, 0, stream>>>(tok_b, qkvW_b, 4224, 1536, 512, 512, 0, 512,
                                               nullptr, 0, 0, qkv, nullptr, qkvb, nullptr, 4224);

  // --- landmark attention (fp32) ---
  k_prep_q<<<1408, 256, 0, stream>>>(qkv, pe_tok, featp, qn);
  k_prep_kv<<<7040, 256, 0, stream>>>(qkv, featp, knT, vc);
  k_landmarks<<<64, 256, 0, stream>>>(qn, knT, qL, kL);
  k_a1<<<1408, 256, 0, stream>>>(qn, kL, a1);
  k_a2_logits<<<dim3(14, 8), 256, 0, stream>>>(qL, knT, E);
  k_a2_pv<<<128, 256, 0, stream>>>(E, vc, tmp);
  k_vals<<<1536, 256, 0, stream>>>(a1, tmp, vals_b);

  // --- output projection -> d_out ---
  k_cast<<<256, 256, 0, stream>>>(ow, oW_b, 65536);
  gemm_bt<<<dim3(4, 6, 1), 256, 0, stream>>>(vals_b, oW_b, 768, 512, 512, 512, 0, 512,
                                             nullptr, 0, 0, out, nullptr, ob, nullptr, 704);
}